// Round 10
// baseline (413.845 us; speedup 1.0000x reference)
//
#include <hip/hip_runtime.h>

typedef __attribute__((ext_vector_type(8))) short bf16x8;
typedef __attribute__((ext_vector_type(4))) float f32x4;
typedef unsigned short u16;
typedef unsigned int u32;

#define NN 8192
#define FD 256

__device__ __forceinline__ u16 f2bf(float f) {
  union { float f; unsigned u; } v; v.f = f;
  unsigned r = v.u + 0x7FFF + ((v.u >> 16) & 1);
  return (u16)(r >> 16);
}

__device__ __forceinline__ bf16x8 ldcvt8(const float* __restrict__ p) {
  f32x4 x0 = *(const f32x4*)p;
  f32x4 x1 = *(const f32x4*)(p + 4);
  bf16x8 t;
  t[0] = (short)f2bf(x0[0]); t[1] = (short)f2bf(x0[1]);
  t[2] = (short)f2bf(x0[2]); t[3] = (short)f2bf(x0[3]);
  t[4] = (short)f2bf(x1[0]); t[5] = (short)f2bf(x1[1]);
  t[6] = (short)f2bf(x1[2]); t[7] = (short)f2bf(x1[3]);
  return t;
}

// ---- K0: zero hp/lg/src/dst ----
__global__ __launch_bounds__(256) void k_zero(float* __restrict__ p) {
  size_t g = (size_t)(blockIdx.x * 256 + threadIdx.x) * 4;
  f32x4 z = {0.f, 0.f, 0.f, 0.f};
  *(f32x4*)(p + g) = z;
}

// ---- K1: Wh = h @ W -> whT[c][r] (bf16), fused src/dst partial dot + atomicAdd ----
__global__ __launch_bounds__(256) void k_wh(const float* __restrict__ h,
                                            const float* __restrict__ W,
                                            const float* __restrict__ a,
                                            u16* __restrict__ whT,
                                            float* __restrict__ src,
                                            float* __restrict__ dst) {
  int tid = threadIdx.x;
  int lane = tid & 63;
  int wv = tid >> 6;
  int r0 = blockIdx.x * 64 + (wv >> 1) * 32;
  int c0 = blockIdx.y * 64 + (wv & 1) * 32;
  int lr = lane & 15;
  int q = lane >> 4;

  f32x4 acc[2][2] = {};
  for (int kk = 0; kk < FD; kk += 32) {
    int kb = kk + q * 8;
    bf16x8 av[2], bv[2];
#pragma unroll
    for (int m = 0; m < 2; m++)
      av[m] = ldcvt8(h + (size_t)(r0 + m * 16 + lr) * FD + kb);
#pragma unroll
    for (int n = 0; n < 2; n++) {
      int col = c0 + n * 16 + lr;
      const float* p = W + (size_t)kb * FD + col;
      bf16x8 t;
#pragma unroll
      for (int e = 0; e < 8; e++) t[e] = (short)f2bf(p[(size_t)e * FD]);
      bv[n] = t;
    }
#pragma unroll
    for (int m = 0; m < 2; m++)
#pragma unroll
      for (int n = 0; n < 2; n++)
        acc[m][n] = __builtin_amdgcn_mfma_f32_16x16x32_bf16(av[m], bv[n], acc[m][n], 0, 0, 0);
  }
#pragma unroll
  for (int m = 0; m < 2; m++)
#pragma unroll
    for (int n = 0; n < 2; n++) {
      int gc = c0 + n * 16 + lr;
      int gr = r0 + m * 16 + q * 4;
      ushort4 st;
      st.x = f2bf(acc[m][n][0]);
      st.y = f2bf(acc[m][n][1]);
      st.z = f2bf(acc[m][n][2]);
      st.w = f2bf(acc[m][n][3]);
      *(ushort4*)(whT + (size_t)gc * NN + gr) = st;
    }
  float aA0 = a[c0 + lr], aA1 = a[c0 + 16 + lr];
  float aB0 = a[256 + c0 + lr], aB1 = a[256 + c0 + 16 + lr];
#pragma unroll
  for (int m = 0; m < 2; m++)
#pragma unroll
    for (int j = 0; j < 4; j++) {
      float s1 = acc[m][0][j] * aA0 + acc[m][1][j] * aA1;
      float s2 = acc[m][0][j] * aB0 + acc[m][1][j] * aB1;
#pragma unroll
      for (int sh = 1; sh < 16; sh <<= 1) {
        s1 += __shfl_xor(s1, sh);
        s2 += __shfl_xor(s2, sh);
      }
      if (lr == 0) {
        int row = r0 + m * 16 + q * 4 + j;
        atomicAdd(&src[row], s1);
        atomicAdd(&dst[row], s2);
      }
    }
}

// ---- K2: attention, barrier-free per-wave streaming ----
// 1024 blocks x 256 thr (3/CU via launch_bounds). Block: 32 rows x j-quarter.
// Wave: 16 rows (w>>1) x 128 cols (w&1), fully independent sweep of 64 steps
// x 32 j. P built directly in A-frag registers (row=lr, j=q*8+e), computed
// once per c-half. whT B-frags global->reg double-buffered (L2-hot 1MB slice,
// jh=bid&3 -> one jh per XCD). adj double-buffered. No barriers, no LDS
// handoff in the loop; latency hidden by 12 independent waves/CU.
__global__ __launch_bounds__(256, 3) void k_att(const float* __restrict__ adj,
                                                const u16* __restrict__ whT,
                                                const float* __restrict__ src,
                                                const float* __restrict__ dst,
                                                float* __restrict__ hp,
                                                float* __restrict__ lg) {
  __shared__ float dst_lds[2048];   // 8KB dst j-slice

  const int tid = threadIdx.x;
  const int lane = tid & 63;
  const int w = tid >> 6;
  const int lr = lane & 15;
  const int q = lane >> 4;
  const int bid = blockIdx.x;
  const int jh = bid & 3;
  const int jb = jh * 2048;
  const int i0r = (bid >> 2) * 32 + (w >> 1) * 16;  // wave's 16 rows
  const int c0 = (w & 1) * 128;                     // wave's c-half

  const float* adjP = adj + (size_t)(i0r + lr) * NN + jb + q * 8;
  const float srcv = src[i0r + lr];
  const u16* wp = whT + (size_t)(c0 + lr) * NN + jb + q * 8;

  {
    f32x4 v0 = *(const f32x4*)(dst + jb + tid * 8);
    f32x4 v1 = *(const f32x4*)(dst + jb + tid * 8 + 4);
    *(f32x4*)&dst_lds[tid * 8] = v0;
    *(f32x4*)&dst_lds[tid * 8 + 4] = v1;
  }
  __syncthreads();   // only barrier: dst_lds ready

  f32x4 acc[8] = {};
  float lsum = 0.f;
  f32x4 aA0, aA1, aB0, aB1;
  bf16x8 BfA[8], BfB[8];
  bf16x8 AF;

#define ALD(T, X, Y)                                                        \
  { X = *(const f32x4*)(adjP + (size_t)(T) * 32);                           \
    Y = *(const f32x4*)(adjP + (size_t)(T) * 32 + 4); }
#define BLD(T, B)                                                           \
  { _Pragma("unroll") for (int cf = 0; cf < 8; cf++)                        \
      B[cf] = *(const bf16x8*)(wp + (size_t)cf * 16 * NN + (T) * 32); }
#define PGEN(T, X, Y)                                                       \
  {                                                                         \
    f32x4 d0 = *(const f32x4*)&dst_lds[(T) * 32 + q * 8];                   \
    f32x4 d1 = *(const f32x4*)&dst_lds[(T) * 32 + q * 8 + 4];               \
    _Pragma("unroll") for (int e = 0; e < 4; e++) {                         \
      float x = srcv + d0[e];                                               \
      x = fmaxf(x, 0.2f * x);                                               \
      float p = X[e] * __expf(x);                                           \
      lsum += p;                                                            \
      AF[e] = (short)f2bf(p);                                               \
    }                                                                       \
    _Pragma("unroll") for (int e = 0; e < 4; e++) {                         \
      float x = srcv + d1[e];                                               \
      x = fmaxf(x, 0.2f * x);                                               \
      float p = Y[e] * __expf(x);                                           \
      lsum += p;                                                            \
      AF[4 + e] = (short)f2bf(p);                                           \
    }                                                                       \
  }
#define CMP(B)                                                              \
  { _Pragma("unroll") for (int cf = 0; cf < 8; cf++)                        \
      acc[cf] = __builtin_amdgcn_mfma_f32_16x16x32_bf16(AF, B[cf], acc[cf], 0, 0, 0); }

  ALD(0, aA0, aA1);
  BLD(0, BfA);
  ALD(1, aB0, aB1);
  BLD(1, BfB);

  for (int t = 0; t < 64; t += 2) {
    PGEN(t, aA0, aA1);
    CMP(BfA);
    if (t + 2 < 64) { ALD(t + 2, aA0, aA1); BLD(t + 2, BfA); }
    PGEN(t + 1, aB0, aB1);
    CMP(BfB);
    if (t + 3 < 64) { ALD(t + 3, aB0, aB1); BLD(t + 3, BfB); }
  }
#undef ALD
#undef BLD
#undef PGEN
#undef CMP

  // row sums: reduce over q-groups; only c-half 0 contributes
  lsum += __shfl_xor(lsum, 16);
  lsum += __shfl_xor(lsum, 32);
  if ((w & 1) == 0 && lane < 16) atomicAdd(&lg[i0r + lane], lsum);

  // acc[cf][j] = C[row=q*4+j][col=cf*16+lr]
#pragma unroll
  for (int cf = 0; cf < 8; cf++)
#pragma unroll
    for (int j = 0; j < 4; j++)
      atomicAdd(&hp[(size_t)(i0r + q * 4 + j) * FD + c0 + cf * 16 + lr],
                acc[cf][j]);
}

// ---- K3: normalize hp by row-sum, cast to bf16 (hpb aliases whT region) ----
__global__ __launch_bounds__(256) void k_norm(const float* __restrict__ hp,
                                              const float* __restrict__ lg,
                                              u16* __restrict__ hpb) {
  int g = blockIdx.x * 1024 + threadIdx.x * 4;
  f32x4 v = *(const f32x4*)(hp + g);
  float inv = 1.0f / lg[g >> 8];
  ushort4 st;
  st.x = f2bf(v[0] * inv);
  st.y = f2bf(v[1] * inv);
  st.z = f2bf(v[2] * inv);
  st.w = f2bf(v[3] * inv);
  *(ushort4*)(hpb + g) = st;
}

// ---- K4: fused GRUCell (h, w_ih, w_hh cast f32->bf16 inline) ----
__global__ __launch_bounds__(256) void k_gru(const u16* __restrict__ hpb,
                                             const float* __restrict__ h,
                                             const float* __restrict__ wih,
                                             const float* __restrict__ whh,
                                             const float* __restrict__ bih,
                                             const float* __restrict__ bhh,
                                             float* __restrict__ out) {
  int tid = threadIdx.x;
  int lane = tid & 63;
  int wv = tid >> 6;
  int i0 = blockIdx.x * 32;
  int lr = lane & 15;
  int q = lane >> 4;
  int c = blockIdx.y * 64 + wv * 16 + lr;
  f32x4 gi[3][2] = {};
  f32x4 gh[3][2] = {};
  for (int kk = 0; kk < FD; kk += 32) {
    int kb = kk + q * 8;
    bf16x8 ap[2], ah[2], bi[3], bh[3];
#pragma unroll
    for (int m = 0; m < 2; m++) {
      ap[m] = *(const bf16x8*)(hpb + (size_t)(i0 + m * 16 + lr) * FD + kb);
      ah[m] = ldcvt8(h + (size_t)(i0 + m * 16 + lr) * FD + kb);
    }
#pragma unroll
    for (int g = 0; g < 3; g++) {
      bi[g] = ldcvt8(wih + (size_t)(g * 256 + c) * FD + kb);
      bh[g] = ldcvt8(whh + (size_t)(g * 256 + c) * FD + kb);
    }
#pragma unroll
    for (int g = 0; g < 3; g++)
#pragma unroll
      for (int m = 0; m < 2; m++) {
        gi[g][m] = __builtin_amdgcn_mfma_f32_16x16x32_bf16(ap[m], bi[g], gi[g][m], 0, 0, 0);
        gh[g][m] = __builtin_amdgcn_mfma_f32_16x16x32_bf16(ah[m], bh[g], gh[g][m], 0, 0, 0);
      }
  }
  float bir = bih[c], biz = bih[256 + c], bin = bih[512 + c];
  float bhr = bhh[c], bhz = bhh[256 + c], bhn = bhh[512 + c];
#pragma unroll
  for (int m = 0; m < 2; m++)
#pragma unroll
    for (int j = 0; j < 4; j++) {
      int row = i0 + m * 16 + q * 4 + j;
      float rv = gi[0][m][j] + bir + gh[0][m][j] + bhr;
      float zv = gi[1][m][j] + biz + gh[1][m][j] + bhz;
      float r = 1.f / (1.f + __expf(-rv));
      float z = 1.f / (1.f + __expf(-zv));
      float nx = gi[2][m][j] + bin + r * (gh[2][m][j] + bhn);
      float n = 1.f - 2.f / (__expf(2.f * nx) + 1.f);
      float hv = h[(size_t)row * FD + c];
      out[(size_t)row * FD + c] = (1.f - z) * n + z * hv;
    }
}

extern "C" void kernel_launch(void* const* d_in, const int* in_sizes, int n_in,
                              void* d_out, int out_size, void* d_ws, size_t ws_size,
                              hipStream_t stream) {
  const float* h   = (const float*)d_in[0];
  const float* adj = (const float*)d_in[1];
  const float* W   = (const float*)d_in[2];
  const float* a   = (const float*)d_in[3];
  const float* wih = (const float*)d_in[4];
  const float* whh = (const float*)d_in[5];
  const float* bih = (const float*)d_in[6];
  const float* bhh = (const float*)d_in[7];
  float* out = (float*)d_out;

  char* ws = (char*)d_ws;
  u16* whT   = (u16*)(ws);                  // [0, 4 MB)   Wh^T bf16; reused as hpb after k_att
  u16* hpb   = (u16*)(ws);                  //   alias — written by k_norm, read by k_gru
  float* hp  = (float*)(ws + 4194304);      // [4 MB, 12 MB) h' f32 accumulators
  float* lg  = (float*)(ws + 12582912);     // 32 KB row sums
  float* srcv = (float*)(ws + 12615680);    // 32 KB
  float* dstv = (float*)(ws + 12648448);    // 32 KB
  (void)ws_size;

  k_zero<<<2072, 256, 0, stream>>>((float*)(ws + 4194304));  // hp+lg+src+dst
  k_wh<<<dim3(128, 4), 256, 0, stream>>>(h, W, a, whT, srcv, dstv);
  k_att<<<1024, 256, 0, stream>>>(adj, whT, srcv, dstv, hp, lg);
  k_norm<<<2048, 256, 0, stream>>>(hp, lg, hpb);
  k_gru<<<dim3(256, 4), 256, 0, stream>>>(hpb, h, wih, whh, bih, bhh, out);
}

// Round 12
// 275.973 us; speedup vs baseline: 1.4996x; 1.4996x over previous
//
#include <hip/hip_runtime.h>

typedef __attribute__((ext_vector_type(8))) short bf16x8;
typedef __attribute__((ext_vector_type(4))) float f32x4;
typedef unsigned short u16;
typedef unsigned int u32;

#define NN 8192
#define FD 256

__device__ __forceinline__ u16 f2bf(float f) {
  union { float f; unsigned u; } v; v.f = f;
  unsigned r = v.u + 0x7FFF + ((v.u >> 16) & 1);
  return (u16)(r >> 16);
}

__device__ __forceinline__ bf16x8 ldcvt8(const float* __restrict__ p) {
  f32x4 x0 = *(const f32x4*)p;
  f32x4 x1 = *(const f32x4*)(p + 4);
  bf16x8 t;
  t[0] = (short)f2bf(x0[0]); t[1] = (short)f2bf(x0[1]);
  t[2] = (short)f2bf(x0[2]); t[3] = (short)f2bf(x0[3]);
  t[4] = (short)f2bf(x1[0]); t[5] = (short)f2bf(x1[1]);
  t[6] = (short)f2bf(x1[2]); t[7] = (short)f2bf(x1[3]);
  return t;
}

// ---- K0: zero hp/lg/src/dst ----
__global__ __launch_bounds__(256) void k_zero(float* __restrict__ p) {
  size_t g = (size_t)(blockIdx.x * 256 + threadIdx.x) * 4;
  f32x4 z = {0.f, 0.f, 0.f, 0.f};
  *(f32x4*)(p + g) = z;
}

// ---- K1: Wh = h @ W -> whT[c][r] (bf16), fused src/dst partial dot + atomicAdd ----
__global__ __launch_bounds__(256) void k_wh(const float* __restrict__ h,
                                            const float* __restrict__ W,
                                            const float* __restrict__ a,
                                            u16* __restrict__ whT,
                                            float* __restrict__ src,
                                            float* __restrict__ dst) {
  int tid = threadIdx.x;
  int lane = tid & 63;
  int wv = tid >> 6;
  int r0 = blockIdx.x * 64 + (wv >> 1) * 32;
  int c0 = blockIdx.y * 64 + (wv & 1) * 32;
  int lr = lane & 15;
  int q = lane >> 4;

  f32x4 acc[2][2] = {};
  for (int kk = 0; kk < FD; kk += 32) {
    int kb = kk + q * 8;
    bf16x8 av[2], bv[2];
#pragma unroll
    for (int m = 0; m < 2; m++)
      av[m] = ldcvt8(h + (size_t)(r0 + m * 16 + lr) * FD + kb);
#pragma unroll
    for (int n = 0; n < 2; n++) {
      int col = c0 + n * 16 + lr;
      const float* p = W + (size_t)kb * FD + col;
      bf16x8 t;
#pragma unroll
      for (int e = 0; e < 8; e++) t[e] = (short)f2bf(p[(size_t)e * FD]);
      bv[n] = t;
    }
#pragma unroll
    for (int m = 0; m < 2; m++)
#pragma unroll
      for (int n = 0; n < 2; n++)
        acc[m][n] = __builtin_amdgcn_mfma_f32_16x16x32_bf16(av[m], bv[n], acc[m][n], 0, 0, 0);
  }
#pragma unroll
  for (int m = 0; m < 2; m++)
#pragma unroll
    for (int n = 0; n < 2; n++) {
      int gc = c0 + n * 16 + lr;
      int gr = r0 + m * 16 + q * 4;
      ushort4 st;
      st.x = f2bf(acc[m][n][0]);
      st.y = f2bf(acc[m][n][1]);
      st.z = f2bf(acc[m][n][2]);
      st.w = f2bf(acc[m][n][3]);
      *(ushort4*)(whT + (size_t)gc * NN + gr) = st;
    }
  float aA0 = a[c0 + lr], aA1 = a[c0 + 16 + lr];
  float aB0 = a[256 + c0 + lr], aB1 = a[256 + c0 + 16 + lr];
#pragma unroll
  for (int m = 0; m < 2; m++)
#pragma unroll
    for (int j = 0; j < 4; j++) {
      float s1 = acc[m][0][j] * aA0 + acc[m][1][j] * aA1;
      float s2 = acc[m][0][j] * aB0 + acc[m][1][j] * aB1;
#pragma unroll
      for (int sh = 1; sh < 16; sh <<= 1) {
        s1 += __shfl_xor(s1, sh);
        s2 += __shfl_xor(s2, sh);
      }
      if (lr == 0) {
        int row = r0 + m * 16 + q * 4 + j;
        atomicAdd(&src[row], s1);
        atomicAdd(&dst[row], s2);
      }
    }
}

// ---- K2: attention. P once into LDS 2-ring; whT B-frags global->reg;
// barrier is lgkm-only (load queues never drain). 1024 blocks x 256 thr
// (4 blocks/CU). Block: 32 rows x j-quarter (jh=bid&3 -> one jh per XCD,
// whT slice L2-hot). Wave = 32 rows x 64 cols (cg=w), acc 2x4 f32x4.
// 64 steps of 32 j. P tile [32][40u16] (80B pitch: write 2-way, b128 read
// 2-way max). adj read exactly once (by P-gen mapping only).
__global__ __launch_bounds__(256, 4) void k_att(const float* __restrict__ adj,
                                                const u16* __restrict__ whT,
                                                const float* __restrict__ src,
                                                const float* __restrict__ dst,
                                                float* __restrict__ hp,
                                                float* __restrict__ lg) {
  __shared__ u16 pbuf[2][1280];     // 2 x 2.5KB P ring, 80B row pitch
  __shared__ float dst_lds[2048];   // 8KB dst j-slice

  const int tid = threadIdx.x;
  const int lane = tid & 63;
  const int cg = tid >> 6;          // wave = c-group (64 cols)
  const int lr = lane & 15;
  const int q = lane >> 4;
  const int bid = blockIdx.x;
  const int jh = bid & 3;
  const int jb = jh * 2048;
  const int i0 = (bid >> 2) * 32;

  // P-gen: thread -> row pr (0..31), 4 j at pj
  const int pr = tid >> 3;
  const int pj = (tid & 7) * 4;
  const float* adjP = adj + (size_t)(i0 + pr) * NN + jb + pj;
  const float srcv = src[i0 + pr];
  const int pw = pr * 40 + pj;      // u16 offset (80B pitch)

  // B-frags: c = cg*64 + ct*16 + lr, 16B at j = t*32 + q*8
  const u16* wp = whT + (size_t)(cg * 64 + lr) * NN + jb + q * 8;

  f32x4 acc[2][4] = {};
  float lsum = 0.f;
  f32x4 ar0, ar1;
  bf16x8 B0[4], B1[4];

#define ALD(T, R) R = *(const f32x4*)(adjP + (size_t)(T) * 32);
#define BLD(T, B)                                                           \
  { _Pragma("unroll") for (int ct = 0; ct < 4; ct++)                        \
      B[ct] = *(const bf16x8*)(wp + (size_t)ct * 16 * NN + (T) * 32); }
#define PGEN(T, R, PB)                                                      \
  {                                                                         \
    f32x4 dv = *(const f32x4*)&dst_lds[(T) * 32 + pj];                      \
    ushort4 st;                                                             \
    { float x = srcv + dv[0]; x = fmaxf(x, 0.2f * x); float p = R[0] * __expf(x); lsum += p; st.x = f2bf(p); } \
    { float x = srcv + dv[1]; x = fmaxf(x, 0.2f * x); float p = R[1] * __expf(x); lsum += p; st.y = f2bf(p); } \
    { float x = srcv + dv[2]; x = fmaxf(x, 0.2f * x); float p = R[2] * __expf(x); lsum += p; st.z = f2bf(p); } \
    { float x = srcv + dv[3]; x = fmaxf(x, 0.2f * x); float p = R[3] * __expf(x); lsum += p; st.w = f2bf(p); } \
    *(ushort4*)&pbuf[PB][pw] = st;                                          \
  }
#define MFMA8(PB, B)                                                        \
  {                                                                         \
    bf16x8 AF0 = *(const bf16x8*)&pbuf[PB][lr * 40 + q * 8];                \
    bf16x8 AF1 = *(const bf16x8*)&pbuf[PB][(16 + lr) * 40 + q * 8];         \
    __builtin_amdgcn_s_setprio(1);                                          \
    _Pragma("unroll") for (int ct = 0; ct < 4; ct++) {                      \
      acc[0][ct] = __builtin_amdgcn_mfma_f32_16x16x32_bf16(AF0, B[ct], acc[0][ct], 0, 0, 0); \
      acc[1][ct] = __builtin_amdgcn_mfma_f32_16x16x32_bf16(AF1, B[ct], acc[1][ct], 0, 0, 0); \
    }                                                                       \
    __builtin_amdgcn_s_setprio(0);                                          \
  }
#define LBARP asm volatile("s_waitcnt lgkmcnt(0)\n\ts_barrier" ::: "memory")

  // prologue
  {
    f32x4 v0 = *(const f32x4*)(dst + jb + tid * 8);
    f32x4 v1 = *(const f32x4*)(dst + jb + tid * 8 + 4);
    *(f32x4*)&dst_lds[tid * 8] = v0;
    *(f32x4*)&dst_lds[tid * 8 + 4] = v1;
  }
  ALD(0, ar0);
  ALD(1, ar1);
  BLD(0, B0);
  BLD(1, B1);
  __syncthreads();                  // dst_lds ready (single full drain)
  PGEN(0, ar0, 0);                  // P(0) -> pbuf[0]
  ALD(2, ar0);
  LBARP;                            // P(0) visible

  for (int t = 0; t < 64; t += 2) {
    // even: compute step t (pbuf[0], B0); stage P(t+1)->pbuf[1]
    PGEN(t + 1, ar1, 1);
    if (t + 3 < 64) ALD(t + 3, ar1);
    MFMA8(0, B0);
    if (t + 2 < 64) BLD(t + 2, B0);
    LBARP;
    // odd: compute step t+1 (pbuf[1], B1); stage P(t+2)->pbuf[0]
    if (t + 2 < 64) {
      PGEN(t + 2, ar0, 0);
      if (t + 4 < 64) ALD(t + 4, ar0);
    }
    MFMA8(1, B1);
    if (t + 3 < 64) BLD(t + 3, B1);
    LBARP;
  }
#undef ALD
#undef BLD
#undef PGEN
#undef MFMA8
#undef LBARP

  // row sums: 8 threads per row
  lsum += __shfl_xor(lsum, 1);
  lsum += __shfl_xor(lsum, 2);
  lsum += __shfl_xor(lsum, 4);
  if ((tid & 7) == 0) atomicAdd(&lg[i0 + pr], lsum);

  // acc[rt][ct][j] -> hp[i0 + rt*16 + q*4 + j][cg*64 + ct*16 + lr]
#pragma unroll
  for (int rt = 0; rt < 2; rt++)
#pragma unroll
    for (int ct = 0; ct < 4; ct++)
#pragma unroll
      for (int j = 0; j < 4; j++)
        atomicAdd(&hp[(size_t)(i0 + rt * 16 + q * 4 + j) * FD + cg * 64 + ct * 16 + lr],
                  acc[rt][ct][j]);
}

// ---- K3: normalize hp by row-sum, cast to bf16 (hpb aliases whT region) ----
__global__ __launch_bounds__(256) void k_norm(const float* __restrict__ hp,
                                              const float* __restrict__ lg,
                                              u16* __restrict__ hpb) {
  int g = blockIdx.x * 1024 + threadIdx.x * 4;
  f32x4 v = *(const f32x4*)(hp + g);
  float inv = 1.0f / lg[g >> 8];
  ushort4 st;
  st.x = f2bf(v[0] * inv);
  st.y = f2bf(v[1] * inv);
  st.z = f2bf(v[2] * inv);
  st.w = f2bf(v[3] * inv);
  *(ushort4*)(hpb + g) = st;
}

// ---- K4: fused GRUCell (h, w_ih, w_hh cast f32->bf16 inline) ----
__global__ __launch_bounds__(256) void k_gru(const u16* __restrict__ hpb,
                                             const float* __restrict__ h,
                                             const float* __restrict__ wih,
                                             const float* __restrict__ whh,
                                             const float* __restrict__ bih,
                                             const float* __restrict__ bhh,
                                             float* __restrict__ out) {
  int tid = threadIdx.x;
  int lane = tid & 63;
  int wv = tid >> 6;
  int i0 = blockIdx.x * 32;
  int lr = lane & 15;
  int q = lane >> 4;
  int c = blockIdx.y * 64 + wv * 16 + lr;
  f32x4 gi[3][2] = {};
  f32x4 gh[3][2] = {};
  for (int kk = 0; kk < FD; kk += 32) {
    int kb = kk + q * 8;
    bf16x8 ap[2], ah[2], bi[3], bh[3];
#pragma unroll
    for (int m = 0; m < 2; m++) {
      ap[m] = *(const bf16x8*)(hpb + (size_t)(i0 + m * 16 + lr) * FD + kb);
      ah[m] = ldcvt8(h + (size_t)(i0 + m * 16 + lr) * FD + kb);
    }
#pragma unroll
    for (int g = 0; g < 3; g++) {
      bi[g] = ldcvt8(wih + (size_t)(g * 256 + c) * FD + kb);
      bh[g] = ldcvt8(whh + (size_t)(g * 256 + c) * FD + kb);
    }
#pragma unroll
    for (int g = 0; g < 3; g++)
#pragma unroll
      for (int m = 0; m < 2; m++) {
        gi[g][m] = __builtin_amdgcn_mfma_f32_16x16x32_bf16(ap[m], bi[g], gi[g][m], 0, 0, 0);
        gh[g][m] = __builtin_amdgcn_mfma_f32_16x16x32_bf16(ah[m], bh[g], gh[g][m], 0, 0, 0);
      }
  }
  float bir = bih[c], biz = bih[256 + c], bin = bih[512 + c];
  float bhr = bhh[c], bhz = bhh[256 + c], bhn = bhh[512 + c];
#pragma unroll
  for (int m = 0; m < 2; m++)
#pragma unroll
    for (int j = 0; j < 4; j++) {
      int row = i0 + m * 16 + q * 4 + j;
      float rv = gi[0][m][j] + bir + gh[0][m][j] + bhr;
      float zv = gi[1][m][j] + biz + gh[1][m][j] + bhz;
      float r = 1.f / (1.f + __expf(-rv));
      float z = 1.f / (1.f + __expf(-zv));
      float nx = gi[2][m][j] + bin + r * (gh[2][m][j] + bhn);
      float n = 1.f - 2.f / (__expf(2.f * nx) + 1.f);
      float hv = h[(size_t)row * FD + c];
      out[(size_t)row * FD + c] = (1.f - z) * n + z * hv;
    }
}

extern "C" void kernel_launch(void* const* d_in, const int* in_sizes, int n_in,
                              void* d_out, int out_size, void* d_ws, size_t ws_size,
                              hipStream_t stream) {
  const float* h   = (const float*)d_in[0];
  const float* adj = (const float*)d_in[1];
  const float* W   = (const float*)d_in[2];
  const float* a   = (const float*)d_in[3];
  const float* wih = (const float*)d_in[4];
  const float* whh = (const float*)d_in[5];
  const float* bih = (const float*)d_in[6];
  const float* bhh = (const float*)d_in[7];
  float* out = (float*)d_out;

  char* ws = (char*)d_ws;
  u16* whT   = (u16*)(ws);                  // [0, 4 MB)   Wh^T bf16; reused as hpb after k_att
  u16* hpb   = (u16*)(ws);                  //   alias — written by k_norm, read by k_gru
  float* hp  = (float*)(ws + 4194304);      // [4 MB, 12 MB) h' f32 accumulators
  float* lg  = (float*)(ws + 12582912);     // 32 KB row sums
  float* srcv = (float*)(ws + 12615680);    // 32 KB
  float* dstv = (float*)(ws + 12648448);    // 32 KB
  (void)ws_size;

  k_zero<<<2072, 256, 0, stream>>>((float*)(ws + 4194304));  // hp+lg+src+dst
  k_wh<<<dim3(128, 4), 256, 0, stream>>>(h, W, a, whT, srcv, dstv);
  k_att<<<1024, 256, 0, stream>>>(adj, whT, srcv, dstv, hp, lg);
  k_norm<<<2048, 256, 0, stream>>>(hp, lg, hpb);
  k_gru<<<dim3(256, 4), 256, 0, stream>>>(hpb, h, wih, whh, bih, bhh, out);
}

// Round 13
// 207.958 us; speedup vs baseline: 1.9900x; 1.3271x over previous
//
#include <hip/hip_runtime.h>

typedef __attribute__((ext_vector_type(8))) short bf16x8;
typedef __attribute__((ext_vector_type(4))) float f32x4;
typedef unsigned short u16;
typedef unsigned int u32;

#define NN 8192
#define FD 256

__device__ __forceinline__ u16 f2bf(float f) {
  union { float f; unsigned u; } v; v.f = f;
  unsigned r = v.u + 0x7FFF + ((v.u >> 16) & 1);
  return (u16)(r >> 16);
}

__device__ __forceinline__ bf16x8 ldcvt8(const float* __restrict__ p) {
  f32x4 x0 = *(const f32x4*)p;
  f32x4 x1 = *(const f32x4*)(p + 4);
  bf16x8 t;
  t[0] = (short)f2bf(x0[0]); t[1] = (short)f2bf(x0[1]);
  t[2] = (short)f2bf(x0[2]); t[3] = (short)f2bf(x0[3]);
  t[4] = (short)f2bf(x1[0]); t[5] = (short)f2bf(x1[1]);
  t[6] = (short)f2bf(x1[2]); t[7] = (short)f2bf(x1[3]);
  return t;
}

__device__ __forceinline__ void gl16(const void* g, void* l) {
  __builtin_amdgcn_global_load_lds((const __attribute__((address_space(1))) u32*)g,
                                   (__attribute__((address_space(3))) u32*)l, 16, 0, 0);
}

// ---- K0: zero src/dst (64 KB) ----
__global__ __launch_bounds__(256) void k_zero(float* __restrict__ p) {
  int g = (blockIdx.x * 256 + threadIdx.x) * 4;
  f32x4 z = {0.f, 0.f, 0.f, 0.f};
  *(f32x4*)(p + g) = z;
}

// ---- K1: Wh = h @ W -> whT[c][r] (bf16), fused src/dst dot + atomicAdd ----
__global__ __launch_bounds__(256) void k_wh(const float* __restrict__ h,
                                            const float* __restrict__ W,
                                            const float* __restrict__ a,
                                            u16* __restrict__ whT,
                                            float* __restrict__ src,
                                            float* __restrict__ dst) {
  int tid = threadIdx.x;
  int lane = tid & 63;
  int wv = tid >> 6;
  int r0 = blockIdx.x * 64 + (wv >> 1) * 32;
  int c0 = blockIdx.y * 64 + (wv & 1) * 32;
  int lr = lane & 15;
  int q = lane >> 4;

  f32x4 acc[2][2] = {};
  for (int kk = 0; kk < FD; kk += 32) {
    int kb = kk + q * 8;
    bf16x8 av[2], bv[2];
#pragma unroll
    for (int m = 0; m < 2; m++)
      av[m] = ldcvt8(h + (size_t)(r0 + m * 16 + lr) * FD + kb);
#pragma unroll
    for (int n = 0; n < 2; n++) {
      int col = c0 + n * 16 + lr;
      const float* p = W + (size_t)kb * FD + col;
      bf16x8 t;
#pragma unroll
      for (int e = 0; e < 8; e++) t[e] = (short)f2bf(p[(size_t)e * FD]);
      bv[n] = t;
    }
#pragma unroll
    for (int m = 0; m < 2; m++)
#pragma unroll
      for (int n = 0; n < 2; n++)
        acc[m][n] = __builtin_amdgcn_mfma_f32_16x16x32_bf16(av[m], bv[n], acc[m][n], 0, 0, 0);
  }
#pragma unroll
  for (int m = 0; m < 2; m++)
#pragma unroll
    for (int n = 0; n < 2; n++) {
      int gc = c0 + n * 16 + lr;
      int gr = r0 + m * 16 + q * 4;
      ushort4 st;
      st.x = f2bf(acc[m][n][0]);
      st.y = f2bf(acc[m][n][1]);
      st.z = f2bf(acc[m][n][2]);
      st.w = f2bf(acc[m][n][3]);
      *(ushort4*)(whT + (size_t)gc * NN + gr) = st;
    }
  float aA0 = a[c0 + lr], aA1 = a[c0 + 16 + lr];
  float aB0 = a[256 + c0 + lr], aB1 = a[256 + c0 + 16 + lr];
#pragma unroll
  for (int m = 0; m < 2; m++)
#pragma unroll
    for (int j = 0; j < 4; j++) {
      float s1 = acc[m][0][j] * aA0 + acc[m][1][j] * aA1;
      float s2 = acc[m][0][j] * aB0 + acc[m][1][j] * aB1;
#pragma unroll
      for (int sh = 1; sh < 16; sh <<= 1) {
        s1 += __shfl_xor(s1, sh);
        s2 += __shfl_xor(s2, sh);
      }
      if (lr == 0) {
        int row = r0 + m * 16 + q * 4 + j;
        atomicAdd(&src[row], s1);
        atomicAdd(&dst[row], s2);
      }
    }
}

// ---- K2: attention, BM=256 x JS=8. 256 blocks (1/CU) x 512 thr (8 waves).
// whT tile (256c x 32j, 16KB) staged per step via global_load_lds (pre-swizzled
// source, conflict-free), 4-slot ring. P computed once/elem into 40-pitch
// double buffer. adj depth-2 register ring. One counted vmcnt(10)+lgkm barrier
// per step AFTER the MFMA cluster; &31 wraparound keeps issue counts constant.
// Traffic: adj 268MB + whT 128MB + partial stores 64MB.
__global__ __launch_bounds__(512, 2) void k_att(const float* __restrict__ adj,
                                                const u16* __restrict__ whT,
                                                const float* __restrict__ src,
                                                const float* __restrict__ dst,
                                                float* __restrict__ hpp,
                                                float* __restrict__ lgp) {
  __shared__ u16 wtile[4][8192];     // 64 KB whT ring
  __shared__ u16 pbuf[2][10240];     // 40 KB P double buffer (pitch 40)
  __shared__ float dst_lds[1024];    // 4 KB

  const int tid = threadIdx.x;
  const int lane = tid & 63;
  const int w = tid >> 6;
  const int lr = lane & 15;
  const int q = lane >> 4;
  const int rg = w >> 1;            // row-group: 64 rows
  const int ch = w & 1;             // c-half: 128 cols
  const int bid = blockIdx.x;
  const int jh = bid & 7;
  const int i0 = (bid >> 3) * 256;
  const int jb = jh * 1024;

  // P-gen: thread -> row pr (0..255), 16 j at pj
  const int pr = tid >> 1;
  const int pj = (tid & 1) * 16;
  const float* adjP = adj + (size_t)(i0 + pr) * NN + jb + pj;
  const float srcv = src[i0 + pr];

  // gl_lds source pre-swizzle: instr k covers c = w*32 + k*16 + (lane>>2),
  // LDS 16B slot s = lane&3 holds global j-slot s ^ ((lane>>2)&3)
  const int gcr = lane >> 2;
  const int jsw = (lane & 3) ^ (gcr & 3);
  const u16* wsrc0 = whT + (size_t)(w * 32 + gcr) * NN + jb + jsw * 8;
  const u16* wsrc1 = wsrc0 + (size_t)16 * NN;

  f32x4 acc[4][8] = {};
  float lsum = 0.f;
  f32x4 arE[4], arO[4];

#define GLDS(T)                                                              \
  {                                                                          \
    int _s = (T) & 3;                                                        \
    gl16(wsrc0 + (size_t)((T) & 31) * 32, &wtile[_s][w * 1024]);             \
    gl16(wsrc1 + (size_t)((T) & 31) * 32, &wtile[_s][w * 1024 + 512]);       \
  }
#define ALD(T, AR)                                                           \
  { _Pragma("unroll") for (int v = 0; v < 4; v++)                            \
      AR[v] = *(const f32x4*)(adjP + (size_t)((T) & 31) * 32 + v * 4); }
#define PGEN(T, AR, PB)                                                      \
  {                                                                          \
    _Pragma("unroll") for (int v = 0; v < 4; v++) {                          \
      f32x4 dv = *(const f32x4*)&dst_lds[((T) & 31) * 32 + pj + v * 4];      \
      ushort4 st;                                                            \
      { float x = srcv + dv[0]; x = fmaxf(x, 0.2f * x); float p = AR[v][0] * __expf(x); lsum += p; st.x = f2bf(p); } \
      { float x = srcv + dv[1]; x = fmaxf(x, 0.2f * x); float p = AR[v][1] * __expf(x); lsum += p; st.y = f2bf(p); } \
      { float x = srcv + dv[2]; x = fmaxf(x, 0.2f * x); float p = AR[v][2] * __expf(x); lsum += p; st.z = f2bf(p); } \
      { float x = srcv + dv[3]; x = fmaxf(x, 0.2f * x); float p = AR[v][3] * __expf(x); lsum += p; st.w = f2bf(p); } \
      *(ushort4*)&pbuf[PB][pr * 40 + pj + v * 4] = st;                       \
    }                                                                        \
  }
#define MSTEP(T, PB)                                                         \
  {                                                                          \
    const u16* bb = &wtile[(T) & 3][0];                                      \
    const u16* pp = &pbuf[PB][0];                                            \
    bf16x8 bfs[8];                                                           \
    _Pragma("unroll") for (int ct = 0; ct < 8; ct++)                         \
      bfs[ct] = *(const bf16x8*)&bb[(ch * 4 + (ct >> 1)) * 1024 + (ct & 1) * 512 + lr * 32 + (q ^ (lr & 3)) * 8]; \
    __builtin_amdgcn_s_setprio(1);                                           \
    _Pragma("unroll") for (int rt = 0; rt < 4; rt++) {                       \
      bf16x8 af = *(const bf16x8*)&pp[(rg * 64 + rt * 16 + lr) * 40 + q * 8]; \
      _Pragma("unroll") for (int ct = 0; ct < 8; ct++)                       \
        acc[rt][ct] = __builtin_amdgcn_mfma_f32_16x16x32_bf16(af, bfs[ct], acc[rt][ct], 0, 0, 0); \
    }                                                                        \
    __builtin_amdgcn_s_setprio(0);                                           \
  }
#define ENDBAR asm volatile("s_waitcnt vmcnt(10) lgkmcnt(0)\n\ts_barrier" ::: "memory")

  // prologue
  if (tid < 256) {
    f32x4 v = *(const f32x4*)(dst + jb + tid * 4);
    *(f32x4*)&dst_lds[tid * 4] = v;
  }
  GLDS(0);
  GLDS(1);
  ALD(0, arE);
  ALD(1, arO);
  __syncthreads();              // full drain: dst_lds + tiles 0,1 + adj 0,1 ready
  PGEN(0, arE, 0);
  ALD(2, arE);
  asm volatile("s_waitcnt lgkmcnt(0)\n\ts_barrier" ::: "memory");  // P(0) visible

  for (int t = 0; t < 32; t += 2) {
    // body t (even): MFMA step t, stage P(t+1), tile t+2, adj t+3
    GLDS(t + 2);
    PGEN(t + 1, arO, 1);
    ALD(t + 3, arO);
    MSTEP(t, 0);
    ENDBAR;
    // body t+1 (odd): MFMA step t+1, stage P(t+2), tile t+3, adj t+4
    GLDS(t + 3);
    PGEN(t + 2, arE, 0);
    ALD(t + 4, arE);
    MSTEP(t + 1, 1);
    ENDBAR;
  }
#undef GLDS
#undef ALD
#undef PGEN
#undef MSTEP
#undef ENDBAR

  // row-sum partial: 2 threads per row
  lsum += __shfl_xor(lsum, 1);
  if ((lane & 1) == 0) lgp[jh * NN + i0 + pr] = lsum;

  // partial h' plain stores: hpp slice jh
  float* hs = hpp + (size_t)jh * NN * FD;
#pragma unroll
  for (int rt = 0; rt < 4; rt++)
#pragma unroll
    for (int ct = 0; ct < 8; ct++) {
      int c = ch * 128 + ct * 16 + lr;
#pragma unroll
      for (int j = 0; j < 4; j++) {
        int row = i0 + rg * 64 + rt * 16 + q * 4 + j;
        hs[(size_t)row * FD + c] = acc[rt][ct][j];
      }
    }
}

// ---- K3: sum 8 partials, normalize by row-sum, cast bf16 (hpb aliases whT) ----
__global__ __launch_bounds__(256) void k_norm(const float* __restrict__ hpp,
                                              const float* __restrict__ lgp,
                                              u16* __restrict__ hpb) {
  int gid = blockIdx.x * 256 + threadIdx.x;
  int idx = gid * 4;
  int row = idx >> 8;
  f32x4 s = {0.f, 0.f, 0.f, 0.f};
  float l = 0.f;
#pragma unroll
  for (int jh = 0; jh < 8; jh++) {
    s += *(const f32x4*)(hpp + (size_t)jh * NN * FD + idx);
    l += lgp[jh * NN + row];
  }
  float inv = 1.0f / l;
  ushort4 st;
  st.x = f2bf(s[0] * inv);
  st.y = f2bf(s[1] * inv);
  st.z = f2bf(s[2] * inv);
  st.w = f2bf(s[3] * inv);
  *(ushort4*)(hpb + idx) = st;
}

// ---- K4: fused GRUCell (h, w_ih, w_hh cast f32->bf16 inline) ----
__global__ __launch_bounds__(256) void k_gru(const u16* __restrict__ hpb,
                                             const float* __restrict__ h,
                                             const float* __restrict__ wih,
                                             const float* __restrict__ whh,
                                             const float* __restrict__ bih,
                                             const float* __restrict__ bhh,
                                             float* __restrict__ out) {
  int tid = threadIdx.x;
  int lane = tid & 63;
  int wv = tid >> 6;
  int i0 = blockIdx.x * 32;
  int lr = lane & 15;
  int q = lane >> 4;
  int c = blockIdx.y * 64 + wv * 16 + lr;
  f32x4 gi[3][2] = {};
  f32x4 gh[3][2] = {};
  for (int kk = 0; kk < FD; kk += 32) {
    int kb = kk + q * 8;
    bf16x8 ap[2], ah[2], bi[3], bh[3];
#pragma unroll
    for (int m = 0; m < 2; m++) {
      ap[m] = *(const bf16x8*)(hpb + (size_t)(i0 + m * 16 + lr) * FD + kb);
      ah[m] = ldcvt8(h + (size_t)(i0 + m * 16 + lr) * FD + kb);
    }
#pragma unroll
    for (int g = 0; g < 3; g++) {
      bi[g] = ldcvt8(wih + (size_t)(g * 256 + c) * FD + kb);
      bh[g] = ldcvt8(whh + (size_t)(g * 256 + c) * FD + kb);
    }
#pragma unroll
    for (int g = 0; g < 3; g++)
#pragma unroll
      for (int m = 0; m < 2; m++) {
        gi[g][m] = __builtin_amdgcn_mfma_f32_16x16x32_bf16(ap[m], bi[g], gi[g][m], 0, 0, 0);
        gh[g][m] = __builtin_amdgcn_mfma_f32_16x16x32_bf16(ah[m], bh[g], gh[g][m], 0, 0, 0);
      }
  }
  float bir = bih[c], biz = bih[256 + c], bin = bih[512 + c];
  float bhr = bhh[c], bhz = bhh[256 + c], bhn = bhh[512 + c];
#pragma unroll
  for (int m = 0; m < 2; m++)
#pragma unroll
    for (int j = 0; j < 4; j++) {
      int row = i0 + m * 16 + q * 4 + j;
      float rv = gi[0][m][j] + bir + gh[0][m][j] + bhr;
      float zv = gi[1][m][j] + biz + gh[1][m][j] + bhz;
      float r = 1.f / (1.f + __expf(-rv));
      float z = 1.f / (1.f + __expf(-zv));
      float nx = gi[2][m][j] + bin + r * (gh[2][m][j] + bhn);
      float n = 1.f - 2.f / (__expf(2.f * nx) + 1.f);
      float hv = h[(size_t)row * FD + c];
      out[(size_t)row * FD + c] = (1.f - z) * n + z * hv;
    }
}

extern "C" void kernel_launch(void* const* d_in, const int* in_sizes, int n_in,
                              void* d_out, int out_size, void* d_ws, size_t ws_size,
                              hipStream_t stream) {
  const float* h   = (const float*)d_in[0];
  const float* adj = (const float*)d_in[1];
  const float* W   = (const float*)d_in[2];
  const float* a   = (const float*)d_in[3];
  const float* wih = (const float*)d_in[4];
  const float* whh = (const float*)d_in[5];
  const float* bih = (const float*)d_in[6];
  const float* bhh = (const float*)d_in[7];
  float* out = (float*)d_out;

  // ws layout (~36.2 MB; harness poison fill shows ws ~1 GB):
  char* ws = (char*)d_ws;
  u16* whT   = (u16*)(ws);                   // [0, 4 MB) Wh^T bf16; aliased by hpb after k_att
  u16* hpb   = (u16*)(ws);                   //   alias
  float* hpp = (float*)(ws + 4194304);       // [4 MB, 68 MB) 8 x h'-partials f32
  float* lgp = (float*)(ws + 71303168);      // 8 x 8192 x 4 = 256 KB row-sum partials
  float* srcv = (float*)(ws + 71565312);     // 32 KB
  float* dstv = (float*)(ws + 71598080);     // 32 KB -> end ~71.6 MB
  (void)ws_size;

  k_zero<<<16, 256, 0, stream>>>(srcv);      // src+dst 64 KB contiguous
  k_wh<<<dim3(128, 4), 256, 0, stream>>>(h, W, a, whT, srcv, dstv);
  k_att<<<256, 512, 0, stream>>>(adj, whT, srcv, dstv, hpp, lgp);
  k_norm<<<2048, 256, 0, stream>>>(hpp, lgp, hpb);
  k_gru<<<dim3(256, 4), 256, 0, stream>>>(hpb, h, wih, whh, bih, bhh, out);
}